// Round 6
// baseline (486.498 us; speedup 1.0000x reference)
//
#include <hip/hip_runtime.h>
#include <hip/hip_bf16.h>
#include <stdint.h>

#define WAY 5
#define SHOT 5
#define QUERY 15
#define DIM 640
#define NMEM 100000
#define NSUP 25              // WAY*SHOT
#define NQ 75                // QUERY*WAY
#define RPB 400              // rows per block in k_sim_topk
#define NBLK 250             // 250*400 = 100000 exactly
#define NCB (NBLK*8)         // block candidates per way = 2000
#define NCAND_M (NCB + SHOT) // merge candidates per way = 2005

// ws layout (fp32 elements) — 23,232 floats ~93 KB (ran without fault R2-R5)
#define WS_A      0          // A[5][640]
#define WS_SIMSUP 3200       // [5][5]
#define WS_CANDV  3232       // [5][2000] float
#define WS_CANDI  13232      // [5][2000] int (alias)

// streaming top-8 insert; maintains current-min slot (mn/ms); rejects NaN
__device__ __forceinline__ void topk_insert(float val, int idx,
                                            float tv[8], int ti[8],
                                            float& mn, int& ms) {
    if (val > mn) {
        tv[ms] = val; ti[ms] = idx;
        mn = tv[0]; ms = 0;
        #pragma unroll
        for (int a = 1; a < 8; a++) if (tv[a] < mn) { mn = tv[a]; ms = a; }
    }
}

// ---------------- kernel 1: support norms, A_w, sim_sup (fp32 inputs) ----------------
__global__ __launch_bounds__(256) void k_prep(const float* __restrict__ inst,
                                              float* __restrict__ ws) {
    __shared__ float rn[NSUP];
    __shared__ float As[WAY][DIM];
    const int tid = threadIdx.x, lane = tid & 63, wv = tid >> 6;

    // 1/norm of each of the 25 support rows (instance rows 0..24)
    for (int r = wv; r < NSUP; r += 4) {
        float s = 0.f;
        for (int k = lane; k < DIM; k += 64) { float x = inst[r*DIM + k]; s += x*x; }
        for (int o = 32; o > 0; o >>= 1) s += __shfl_down(s, o, 64);
        if (lane == 0) rn[r] = 1.f / fmaxf(sqrtf(s), 1e-12f);
    }
    __syncthreads();

    // A[w][d] = sum_s inst[s*WAY+w][d] * rn[s*WAY+w]
    for (int p = tid; p < WAY*DIM; p += 256) {
        int w = p / DIM, d = p % DIM;
        float a = 0.f;
        #pragma unroll
        for (int s = 0; s < SHOT; s++) {
            int r = s*WAY + w;
            a = fmaf(inst[r*DIM + d], rn[r], a);
        }
        As[w][d] = a;
        ws[WS_A + p] = a;
    }
    __syncthreads();

    // sim_sup[w][t] = 0.2 * rn[t*WAY+w] * dot(A[w], inst[t*WAY+w])
    for (int p = wv; p < 25; p += 4) {
        int w = p / 5, t = p % 5, r = t*WAY + w;
        float s = 0.f;
        for (int k = lane; k < DIM; k += 64) s = fmaf(As[w][k], inst[r*DIM + k], s);
        for (int o = 32; o > 0; o >>= 1) s += __shfl_down(s, o, 64);
        if (lane == 0) ws[WS_SIMSUP + p] = 0.2f * rn[r] * s;
    }
}

// ------- kernel 2: sims for 400 rows/block + per-block top-8 per way -------
// 320 threads = 5 waves; wave v owns way v for the top-k phases.
__global__ __launch_bounds__(320) void k_sim_topk(const float* __restrict__ mem,
                                                  float* __restrict__ ws) {
    __shared__ float As[WAY][DIM];       // 12.8 KB
    __shared__ float sim[WAY][RPB];      // 8 KB
    __shared__ float mv[WAY][64][8];     // 10.24 KB
    __shared__ int   mi[WAY][64][8];     // 10.24 KB
    for (int p = threadIdx.x; p < WAY*DIM; p += 320) ((float*)As)[p] = ws[WS_A + p];
    __syncthreads();

    const int lane = threadIdx.x & 63, wv = threadIdx.x >> 6;  // wv in 0..4
    const int sub = lane >> 4;   // row-within-group 0..3
    const int c   = lane & 15;   // column lane 0..15
    const int base = blockIdx.x * RPB;

    // 20 passes; each pass: 20 rows (5 waves x 4 rows), 16 lanes x float4 per row,
    // 10 independent 16B loads per lane per row -> ILP latency hiding
    for (int p = 0; p < RPB/20; p++) {
        const int lr = p*20 + wv*4 + sub;
        const int row = base + lr;                   // < NMEM (250*400 exact)
        const float4* rp = reinterpret_cast<const float4*>(mem + (size_t)row * DIM);
        float acc[WAY] = {0,0,0,0,0};
        float nn = 0.f;
        #pragma unroll
        for (int it = 0; it < 10; it++) {
            const float4 u = rp[it*16 + c];
            const int col = it*64 + c*4;
            nn = fmaf(u.x,u.x, fmaf(u.y,u.y, fmaf(u.z,u.z, fmaf(u.w,u.w, nn))));
            #pragma unroll
            for (int v = 0; v < WAY; v++) {
                const float4 a = *reinterpret_cast<const float4*>(&As[v][col]);
                acc[v] = fmaf(a.x,u.x, fmaf(a.y,u.y, fmaf(a.z,u.z, fmaf(a.w,u.w, acc[v]))));
            }
        }
        // reduce across the 16 column-lanes (result lands on c==0)
        #pragma unroll
        for (int o = 8; o > 0; o >>= 1) {
            nn += __shfl_down(nn, o, 64);
            #pragma unroll
            for (int v = 0; v < WAY; v++) acc[v] += __shfl_down(acc[v], o, 64);
        }
        if (c == 0) {
            const float sc = 0.2f / fmaxf(sqrtf(nn), 1e-12f);
            #pragma unroll
            for (int v = 0; v < WAY; v++) sim[v][lr] = acc[v] * sc;
        }
    }
    __syncthreads();

    // stage 1: per-lane top-8 over way wv's sims
    float tv[8]; int ti[8]; float mn = -3e38f; int ms = 0;
    #pragma unroll
    for (int j = 0; j < 8; j++) { tv[j] = -3e38f; ti[j] = 0; }
    for (int j = lane; j < RPB; j += 64)
        topk_insert(sim[wv][j], base + j, tv, ti, mn, ms);
    #pragma unroll
    for (int k = 0; k < 8; k++) { mv[wv][lane][k] = tv[k]; mi[wv][lane][k] = ti[k]; }
    __syncthreads();

    // stage 2: 6-step tree merge within each way
    for (int s = 32; s >= 1; s >>= 1) {
        if (lane < s) {
            #pragma unroll
            for (int j = 0; j < 8; j++)
                topk_insert(mv[wv][lane + s][j], mi[wv][lane + s][j], tv, ti, mn, ms);
            #pragma unroll
            for (int j = 0; j < 8; j++) { mv[wv][lane][j] = tv[j]; mi[wv][lane][j] = ti[j]; }
        }
        __syncthreads();
    }
    if (lane == 0) {
        #pragma unroll
        for (int k = 0; k < 8; k++) {
            const int cslot = wv*NCB + blockIdx.x*8 + k;
            ws[WS_CANDV + cslot] = tv[k];
            ((int*)ws)[WS_CANDI + cslot] = ti[k];   // global memory row id
        }
    }
}

// ------- kernel 3: merge top-8, proto, normalize, logits (1 block x 640) -------
__global__ __launch_bounds__(640) void k_final(const float* __restrict__ inst,
                                               const float* __restrict__ mem,
                                               const float* __restrict__ ws,
                                               float* __restrict__ out) {
    __shared__ float mv[WAY][64][8];     // 10.24 KB
    __shared__ int   mi[WAY][64][8];     // 10.24 KB
    __shared__ float topv[WAY][8];
    __shared__ int   topi[WAY][8];
    __shared__ float proto[WAY][DIM];
    __shared__ float pscale[WAY];
    const int tid = threadIdx.x, lane = tid & 63, wave = tid >> 6;  // 10 waves

    // phase 0a: waves 0..4 scan way v's 2005 candidates, per-lane top-8
    float tv[8]; int ti[8]; float mn = -3e38f; int ms = 0;
    #pragma unroll
    for (int j = 0; j < 8; j++) { tv[j] = -3e38f; ti[j] = 0; }
    if (wave < WAY) {
        const int v = wave;
        for (int j = lane; j < NCAND_M; j += 64) {
            float val; int enc;
            if (j < SHOT) { val = ws[WS_SIMSUP + v*5 + j]; enc = j; }
            else {
                const int jj = j - SHOT;
                val = ws[WS_CANDV + v*NCB + jj];
                enc = SHOT + ((const int*)ws)[WS_CANDI + v*NCB + jj];
            }
            topk_insert(val, enc, tv, ti, mn, ms);
        }
        #pragma unroll
        for (int k = 0; k < 8; k++) { mv[v][lane][k] = tv[k]; mi[v][lane][k] = ti[k]; }
    }
    __syncthreads();

    // phase 0b: tree merge per way; lane 0 of waves 0..4 ends with final top-8
    for (int s = 32; s >= 1; s >>= 1) {
        if (wave < WAY && lane < s) {
            #pragma unroll
            for (int j = 0; j < 8; j++)
                topk_insert(mv[wave][lane + s][j], mi[wave][lane + s][j], tv, ti, mn, ms);
            #pragma unroll
            for (int j = 0; j < 8; j++) { mv[wave][lane][j] = tv[j]; mi[wave][lane][j] = ti[j]; }
        }
        __syncthreads();
    }
    if (wave < WAY && lane == 0) {
        #pragma unroll
        for (int k = 0; k < 8; k++) { topv[wave][k] = tv[k]; topi[wave][k] = ti[k]; }
    }
    __syncthreads();

    // phase 1: proto[w][d] = (sum_j val_j * vec_j[d]) / (sum_j val_j)
    {
        const int d = tid;  // exactly 640 threads
        #pragma unroll
        for (int w = 0; w < WAY; w++) {
            float den = 0.f, num = 0.f;
            #pragma unroll
            for (int j = 0; j < 8; j++) {
                const float wt = topv[w][j];
                if (!(wt > -1e29f)) continue;   // NaN-rejecting sentinel guard (inert on real data)
                int id = topi[w][j];
                id = id < 0 ? 0 : (id > NMEM + SHOT - 1 ? NMEM + SHOT - 1 : id);
                const float* row = (id < SHOT)
                    ? (inst + (size_t)(id*WAY + w) * DIM)
                    : (mem + (size_t)(id - SHOT) * DIM);
                den += wt;
                num = fmaf(wt, row[d], num);
            }
            proto[w][d] = num / fmaxf(den, 1e-20f);
        }
    }
    __syncthreads();

    // phase 2: pscale[w] = 1/(max(||proto_w||,eps) * TEMPERATURE)
    if (wave < WAY) {
        const int w = wave;
        float s = 0.f;
        for (int k = lane; k < DIM; k += 64) { float x = proto[w][k]; s += x*x; }
        for (int o = 32; o > 0; o >>= 1) s += __shfl_down(s, o, 64);
        if (lane == 0) pscale[w] = 1.f / (fmaxf(sqrtf(s), 1e-12f) * 64.0f);
    }
    __syncthreads();

    // phase 3: logits[i][w] = dot(query_i, proto_w) * pscale[w]  (fp32 output!)
    if (tid < NQ * WAY) {
        const int i = tid / WAY, w = tid % WAY;
        const float* q = inst + (size_t)(NSUP + i) * DIM;
        float s = 0.f;
        for (int k = 0; k < DIM; k++) s = fmaf(q[k], proto[w][k], s);
        out[tid] = s * pscale[w];
    }
}

extern "C" void kernel_launch(void* const* d_in, const int* in_sizes, int n_in,
                              void* d_out, int out_size, void* d_ws, size_t ws_size,
                              hipStream_t stream) {
    const float* inst = (const float*)d_in[0];   // fp32, 100x640
    const float* mem  = (const float*)d_in[1];   // fp32, 100000x640
    float* ws = (float*)d_ws;
    float* out = (float*)d_out;                  // fp32, 75x5

    k_prep    <<<1,    256, 0, stream>>>(inst, ws);
    k_sim_topk<<<NBLK, 320, 0, stream>>>(mem, ws);
    k_final   <<<1,    640, 0, stream>>>(inst, mem, ws, out);
}